// Round 3
// baseline (276.449 us; speedup 1.0000x reference)
//
#include <hip/hip_runtime.h>
#include <hip/hip_bf16.h>

// Embedding gather: out[token, :] = weight[idx[token], :]
// idx:    (B*S) = 16384   int32
// weight: (50257, 1024)   fp32
// out:    (16384, 1024)   fp32
//
// 2048 blocks x 256 threads, 8 tokens per block. Each thread loads its
// float4 lane of 8 different rows back-to-back (8 loads in flight -> HBM
// latency hidden by ILP, not just occupancy), then stores all 8 with
// nontemporal stores (output has no reuse; keep weight rows in L2/L3 for
// duplicate-row hits).
//
// Use a native clang vector type: __builtin_nontemporal_store rejects
// HIP_vector_type<float,4>.

#define HIDDEN 1024
#define TOKENS_PER_BLOCK 8

typedef float f32x4 __attribute__((ext_vector_type(4)));

__global__ __launch_bounds__(256) void embed_gather_kernel(
    const int* __restrict__ idx,
    const float* __restrict__ weight,
    float* __restrict__ out,
    int n_tokens)
{
    const int t0 = blockIdx.x * TOKENS_PER_BLOCK;
    const int lane = threadIdx.x;  // float4 index within the 1024-float row

    f32x4 v[TOKENS_PER_BLOCK];

    #pragma unroll
    for (int t = 0; t < TOKENS_PER_BLOCK; ++t) {
        const int tok = t0 + t;
        if (tok < n_tokens) {
            const int row = idx[tok];  // wave-uniform -> scalar load
            const f32x4* __restrict__ src =
                reinterpret_cast<const f32x4*>(weight + (size_t)row * HIDDEN);
            v[t] = src[lane];
        }
    }

    #pragma unroll
    for (int t = 0; t < TOKENS_PER_BLOCK; ++t) {
        const int tok = t0 + t;
        if (tok < n_tokens) {
            f32x4* __restrict__ dst =
                reinterpret_cast<f32x4*>(out + (size_t)tok * HIDDEN);
            __builtin_nontemporal_store(v[t], dst + lane);
        }
    }
}

extern "C" void kernel_launch(void* const* d_in, const int* in_sizes, int n_in,
                              void* d_out, int out_size, void* d_ws, size_t ws_size,
                              hipStream_t stream) {
    const int* idx = (const int*)d_in[0];          // 16384 tokens
    const float* weight = (const float*)d_in[1];   // 50257 * 1024
    float* out = (float*)d_out;                    // 16384 * 1024

    const int n_tokens = in_sizes[0];
    const int n_blocks = (n_tokens + TOKENS_PER_BLOCK - 1) / TOKENS_PER_BLOCK;

    embed_gather_kernel<<<n_blocks, 256, 0, stream>>>(idx, weight, out, n_tokens);
}

// Round 4
// 269.935 us; speedup vs baseline: 1.0241x; 1.0241x over previous
//
#include <hip/hip_runtime.h>
#include <hip/hip_bf16.h>

// Embedding gather: out[token, :] = weight[idx[token], :]
// idx:    (B*S) = 16384   int32
// weight: (50257, 1024)   fp32
// out:    (16384, 1024)   fp32
//
// One block per token, 256 threads, each thread moves one float4 (16 B).
// Rows are 4 KiB-aligned -> fully coalesced dwordx4 loads/stores; idx[token]
// is wave-uniform -> scalar load + broadcast.
//
// Measured (R1 vs R3): kernel ~22 us, at the ~20-25 us memory roofline
// (~57 MB unique weight rows + 64 MB output at 5-6 TB/s random-row gather).
// ILP/nontemporal variant (8 tokens/block) did NOT help -> occupancy alone
// (64 blocks/CU of trivial copy work) already hides HBM latency. dur_us is
// dominated by ~250 us of harness poison-fills we can't affect.

#define HIDDEN 1024

__global__ __launch_bounds__(256) void embed_gather_kernel(
    const int* __restrict__ idx,
    const float* __restrict__ weight,
    float* __restrict__ out)
{
    const int token = blockIdx.x;
    const int row = idx[token];  // wave-uniform -> scalar load + broadcast

    const float4* __restrict__ src =
        reinterpret_cast<const float4*>(weight + (size_t)row * HIDDEN);
    float4* __restrict__ dst =
        reinterpret_cast<float4*>(out + (size_t)token * HIDDEN);

    dst[threadIdx.x] = src[threadIdx.x];
}

extern "C" void kernel_launch(void* const* d_in, const int* in_sizes, int n_in,
                              void* d_out, int out_size, void* d_ws, size_t ws_size,
                              hipStream_t stream) {
    const int* idx = (const int*)d_in[0];          // 16384 tokens
    const float* weight = (const float*)d_in[1];   // 50257 * 1024
    float* out = (float*)d_out;                    // 16384 * 1024

    const int n_tokens = in_sizes[0];

    embed_gather_kernel<<<n_tokens, 256, 0, stream>>>(idx, weight, out);
}